// Round 16
// baseline (125.099 us; speedup 1.0000x reference)
//
#include <hip/hip_runtime.h>
#include <hip/hip_bf16.h>

// GraphAttentionLayer: out = elu( softmax_row( where(adj>0, lrelu(src_i+dst_j), 0) ) @ wh )
//
// R15 post-mortem: fused k2 is structurally latency-limited — load dests are
// VGPRs, so in-flight bytes/CU cap at ~3KB vs ~9KB needed (Little's law).
// Six rounds of schedule work moved it 95->75us; the wall is architectural.
// R16: R10's decomposition (measured: mask-k2 ~15us) with the one fix R11
// proved: k0_pack uses PLAIN CACHED loads (37us/pass vs 95 with nt).
//   k0: adj -> 1-bit mask (8MB), 1 row/wave, 1KB/instr contiguous, 32 w/CU.
//   k2: zero adj vmem; masks via wave-uniform s_load; B LDS-resident;
//       P wave-private LDS; row-sums via 5th MFMA (ones-column B).
// Predicted: 37 + 8 + 15 + 6 + ~3 = ~69us total.

constexpr int N_ROWS = 8192;
constexpr int F_IN   = 128;
constexpr int F_OUT  = 64;
#define LRELU_A 0.2f
#define LOG2E   1.4426950408889634f

// workspace layout (bytes)
constexpr size_t OFF_WHT  = 0;                     // 1 MiB bf16 [f][row]
constexpr size_t OFF_SRC  = 1048576;               // 8192 f32 (x log2e)
constexpr size_t OFF_DST  = OFF_SRC + 32768;       // 8192 f32 (x log2e)
constexpr size_t OFF_LP   = OFF_DST + 32768;       // S*8192 f32
constexpr size_t OFF_ACC  = OFF_LP + 16 * 32768;   // 16*8192*64 f32 = 32 MiB
constexpr size_t OFF_MASK = OFF_ACC + 33554432;    // 8192 rows x 1 KiB = 8 MiB

typedef __attribute__((ext_vector_type(4))) float f32x4;
typedef __attribute__((ext_vector_type(2))) float f32x2;
typedef __attribute__((ext_vector_type(4))) int   i32x4;
typedef __attribute__((ext_vector_type(8))) short s16x8;
typedef __attribute__((ext_vector_type(2))) unsigned long long u64x2;

static __device__ __forceinline__ short f2bf(float f) {
  unsigned u = __float_as_uint(f);
  u = (u + 0x7fffu + ((u >> 16) & 1u)) >> 16;  // RNE
  return (short)u;
}

// ---------------- Kernel 0: adj -> bitmask (contiguous, PLAIN cached) -------
// 8192 waves; wave w packs row w: 32 iters x 1KB contiguous reads.
__global__ __launch_bounds__(256) void k0_pack(
    const int* __restrict__ adj, unsigned long long* __restrict__ maskb)
{
  const int lane = threadIdx.x & 63;
  const int w    = blockIdx.x * 4 + (threadIdx.x >> 6);   // row index
  const int* base = adj + (size_t)w * N_ROWS + lane * 4;

  i32x4 cur = *(const i32x4*)(base);
#pragma unroll
  for (int it = 0; it < 32; ++it) {
    i32x4 nxt = cur;
    if (it + 1 < 32)
      nxt = *(const i32x4*)(base + (it + 1) * 256);
    const unsigned long long b0 = __ballot(cur.x > 0);
    const unsigned long long b1 = __ballot(cur.y > 0);
    const unsigned long long b2 = __ballot(cur.z > 0);
    const unsigned long long b3 = __ballot(cur.w > 0);
    if (lane < 4) {
      const unsigned long long v = lane == 0 ? b0 : lane == 1 ? b1
                                 : lane == 2 ? b2 : b3;
      maskb[((size_t)w * 32 + it) * 4 + lane] = v;   // 32B contiguous
    }
    cur = nxt;
  }
}

// ---------------- Kernel 1: wh = x@w ; src/dst (x log2e) ; whT (bf16) -------
__global__ __launch_bounds__(256) void k1_proj(
    const float* __restrict__ x, const float* __restrict__ w,
    const float* __restrict__ a, short* __restrict__ whT,
    float* __restrict__ src, float* __restrict__ dst)
{
  const int lane = threadIdx.x & 63;
  const int wid  = threadIdx.x >> 6;
  const int rowBase = blockIdx.x * 32 + wid * 8;

  float acc[8];
#pragma unroll
  for (int r = 0; r < 8; ++r) acc[r] = 0.0f;

#pragma unroll 1
  for (int kc = 0; kc < 4; ++kc) {
    float wreg[32];
#pragma unroll
    for (int kk = 0; kk < 32; ++kk)
      wreg[kk] = w[(kc * 32 + kk) * F_OUT + lane];
#pragma unroll
    for (int r = 0; r < 8; ++r) {
      const f32x4* xp = (const f32x4*)(x + (size_t)(rowBase + r) * F_IN + kc * 32);
#pragma unroll
      for (int q = 0; q < 8; ++q) {
        f32x4 xv = xp[q];
        acc[r] = fmaf(xv.x, wreg[4*q+0], acc[r]);
        acc[r] = fmaf(xv.y, wreg[4*q+1], acc[r]);
        acc[r] = fmaf(xv.z, wreg[4*q+2], acc[r]);
        acc[r] = fmaf(xv.w, wreg[4*q+3], acc[r]);
      }
    }
  }

  s16x8 hb;
#pragma unroll
  for (int r = 0; r < 8; ++r) hb[r] = f2bf(acc[r]);
  *(s16x8*)&whT[(size_t)lane * N_ROWS + rowBase] = hb;

  const float aS = a[lane];
  const float aD = a[F_OUT + lane];
#pragma unroll
  for (int r = 0; r < 8; ++r) {
    float ts = acc[r] * aS;
    float td = acc[r] * aD;
#pragma unroll
    for (int off = 32; off > 0; off >>= 1) {
      ts += __shfl_xor(ts, off, 64);
      td += __shfl_xor(td, off, 64);
    }
    if (lane == 0) {
      src[rowBase + r] = ts * LOG2E;
      dst[rowBase + r] = td * LOG2E;
    }
  }
}

// ---------------- Kernel 2: mask-driven fused exp+PV (no loop vmem) ---------
// grid: (N/128, 16) x 512 thr (8 waves x 16 rows). LDS: B 64KB + P 8x4KB.
template<int S>
__global__ __launch_bounds__(512, 2) void k2_attn(
    const unsigned long long* __restrict__ maskb, const short* __restrict__ whT,
    const float* __restrict__ src, const float* __restrict__ dst,
    float* __restrict__ acc_part, float* __restrict__ l_part)
{
  constexpr int JLEN = N_ROWS / S;    // 512
  __shared__ short Blds[64 * JLEN];   // 64KB, byte ^= (f&7)<<4
  __shared__ short Plds[8][16 * 128]; // 8 x 4KB wave-private, ^= (r&7)<<4

  const int tid  = threadIdx.x;
  const int lane = tid & 63;
  const int wid  = tid >> 6;
  const int s    = blockIdx.y;
  const int jbase = s * JLEN;
  const int jg0   = jbase / 256;      // first 256-col group
  const int rowg  = blockIdx.x * 128 + wid * 16;
  const int r16   = lane & 15;
  const int kq    = lane >> 4;

  // ---- stage B slice (swizzled); ONE barrier in the whole kernel ----
#pragma unroll
  for (int q = 0; q < 8; ++q) {
    const int m   = tid + q * 512;
    const int f   = m >> 6;
    const int c16 = m & 63;
    const s16x8 v = *(const s16x8*)(whT + (size_t)f * N_ROWS + jbase + c16 * 8);
    *(s16x8*)((char*)Blds + f * (JLEN * 2) + ((c16 * 16) ^ ((f & 7) << 4))) = v;
  }
  __syncthreads();

  // preloads (all loop inputs -> registers/SGPRs)
  f32x2 dstv[4];
#pragma unroll
  for (int c = 0; c < 4; ++c)
    dstv[c] = *(const f32x2*)(dst + jbase + c * 128 + lane * 2);
  const int shiftLo = lane >> 1;          // bit index within dword
  const bool lodd = lane & 1;
  s16x8 bones;
#pragma unroll
  for (int j = 0; j < 8; ++j) bones[j] = (short)((r16 == 0) ? 0x3F80 : 0);

  f32x4 acc0 = {0,0,0,0}, acc1 = {0,0,0,0}, acc2 = {0,0,0,0}, acc3 = {0,0,0,0};
  f32x4 accl = {0,0,0,0};   // row-sums via ones-column MFMA
  short* const myP = &Plds[wid][0];

#pragma unroll
  for (int c = 0; c < 4; ++c) {
    const int gofs = (jg0 + (c >> 1)) * 4;      // u64 index of group in row
    const int shA  = (c & 1) * 32 + shiftLo;    // 64-bit shift amount
    // ---- phase A: 16 rows, 2 cols/lane, mask via s_load ----
#pragma unroll
    for (int r = 0; r < 16; ++r) {
      const float sv = src[rowg + r];           // uniform -> scalar load
      const u64x2* mp = (const u64x2*)(maskb + (size_t)(rowg + r) * 128 + gofs);
      const u64x2 mlo = mp[0];                  // m0, m1
      const u64x2 mhi = mp[1];                  // m2, m3
      const unsigned long long mSelA = lodd ? mhi.x : mlo.x;  // s=2(l&1)
      const unsigned long long mSelB = lodd ? mhi.y : mlo.y;  // s=2(l&1)+1
      const bool bA = (mSelA >> shA) & 1;
      const bool bB = (mSelB >> shA) & 1;
      float e0 = sv + dstv[c].x; e0 = fmaxf(e0, LRELU_A * e0);
      float e1 = sv + dstv[c].y; e1 = fmaxf(e1, LRELU_A * e1);
      const float p0 = bA ? __builtin_amdgcn_exp2f(e0) : 1.0f;
      const float p1 = bB ? __builtin_amdgcn_exp2f(e1) : 1.0f;
      union { unsigned u; __hip_bfloat16 b[2]; } pk;
      pk.b[0] = __float2bfloat16(p0); pk.b[1] = __float2bfloat16(p1);
      *(unsigned*)((char*)myP + r * 256 + ((lane * 4) ^ ((r & 7) << 4))) = pk.u;
    }
    // ---- phase B: MFMA from wave-private P + block B (in-order DS => safe) --
#pragma unroll
    for (int kcc = 0; kcc < 4; ++kcc) {
      const s16x8 af = *(const s16x8*)((char*)myP + r16 * 256
                        + ((kcc * 64 + kq * 16) ^ ((r16 & 7) << 4)));
      const int colb = (c * 128 + kcc * 32 + kq * 8) * 2;
#define BLD(ft) (*(const s16x8*)((char*)Blds + ((ft) * 16 + r16) * (JLEN * 2) \
                  + (colb ^ ((((ft) * 16 + r16) & 7) << 4))))
      acc0 = __builtin_amdgcn_mfma_f32_16x16x32_bf16(af, BLD(0), acc0, 0, 0, 0);
      acc1 = __builtin_amdgcn_mfma_f32_16x16x32_bf16(af, BLD(1), acc1, 0, 0, 0);
      acc2 = __builtin_amdgcn_mfma_f32_16x16x32_bf16(af, BLD(2), acc2, 0, 0, 0);
      acc3 = __builtin_amdgcn_mfma_f32_16x16x32_bf16(af, BLD(3), acc3, 0, 0, 0);
      accl = __builtin_amdgcn_mfma_f32_16x16x32_bf16(af, bones, accl, 0, 0, 0);
#undef BLD
    }
  }

  // ---- epilogue ----
  // C/D: col = lane&15, row = (lane>>4)*4 + reg
  if (r16 == 0) {
#pragma unroll
    for (int rg = 0; rg < 4; ++rg)
      l_part[(size_t)s * N_ROWS + rowg + kq * 4 + rg] = accl[rg];
  }
#define STORE_ACC(av, nt) _Pragma("unroll") \
  for (int rg = 0; rg < 4; ++rg) { \
    const int row = rowg + kq * 4 + rg; \
    __builtin_nontemporal_store((av)[rg], \
        acc_part + ((size_t)s * N_ROWS + row) * F_OUT + (nt) * 16 + r16); \
  }
  STORE_ACC(acc0, 0) STORE_ACC(acc1, 1) STORE_ACC(acc2, 2) STORE_ACC(acc3, 3)
#undef STORE_ACC
}

// ---------------- Kernel 3: combine partials, normalize, ELU ----------------
template<int S>
__global__ __launch_bounds__(256) void k3_combine(
    const float* __restrict__ acc_part, const float* __restrict__ l_part,
    float* __restrict__ out)
{
  const int idx = blockIdx.x * 256 + threadIdx.x;
  const int row = idx >> 4;
  const int f4  = idx & 15;
  f32x4 h = {0.f, 0.f, 0.f, 0.f};
  float l = 0.f;
#pragma unroll
  for (int s = 0; s < S; ++s) {
    h += *(const f32x4*)(acc_part + ((size_t)s * N_ROWS + row) * F_OUT + 4 * f4);
    l += l_part[(size_t)s * N_ROWS + row];
  }
  const float inv = 1.0f / l;
  f32x4 o;
  {
    float v0 = h.x * inv; o.x = v0 > 0.f ? v0 : (__expf(v0) - 1.0f);
    float v1 = h.y * inv; o.y = v1 > 0.f ? v1 : (__expf(v1) - 1.0f);
    float v2 = h.z * inv; o.z = v2 > 0.f ? v2 : (__expf(v2) - 1.0f);
    float v3 = h.w * inv; o.w = v3 > 0.f ? v3 : (__expf(v3) - 1.0f);
  }
  *(f32x4*)(out + (size_t)row * F_OUT + 4 * f4) = o;
}

// ---------------- launch ----------------
extern "C" void kernel_launch(void* const* d_in, const int* in_sizes, int n_in,
                              void* d_out, int out_size, void* d_ws, size_t ws_size,
                              hipStream_t stream) {
  const float* x   = (const float*)d_in[0];
  const int*   adj = (const int*)d_in[1];
  const float* w   = (const float*)d_in[2];
  const float* a   = (const float*)d_in[3];
  float* out = (float*)d_out;
  char* ws = (char*)d_ws;

  short* whT      = (short*)(ws + OFF_WHT);
  float* src      = (float*)(ws + OFF_SRC);
  float* dst      = (float*)(ws + OFF_DST);
  float* l_part   = (float*)(ws + OFF_LP);
  float* acc_part = (float*)(ws + OFF_ACC);
  unsigned long long* maskb = (unsigned long long*)(ws + OFF_MASK);

  k0_pack<<<N_ROWS / 4, 256, 0, stream>>>(adj, maskb);
  k1_proj<<<N_ROWS / 32, 256, 0, stream>>>(x, w, a, whT, src, dst);
  k2_attn<16><<<dim3(N_ROWS / 128, 16), 512, 0, stream>>>(maskb, whT, src, dst,
                                                          acc_part, l_part);
  k3_combine<16><<<(N_ROWS * F_OUT / 4) / 256, 256, 0, stream>>>(acc_part, l_part, out);
}

// Round 17
// 87.768 us; speedup vs baseline: 1.4253x; 1.4253x over previous
//
#include <hip/hip_runtime.h>
#include <hip/hip_bf16.h>

// GraphAttentionLayer: out = elu( softmax_row( where(adj>0, lrelu(src_i+dst_j), 0) ) @ wh )
//
// R16 post-mortem: decomposed path (k0 mask) reads adj cold at the SAME ~90us
// as everything else — R11's "37us/pass" was L3-warm repeats, not cold rate.
// Decomposition = strictly worse (extra k2-mask cost). R12 fused k2 (75us) is
// ~78% of achievable BW on its aggregate 368MB traffic; scatter penalty
// (~1.25x) resisted 5 structural attacks.
// R17: R12 verbatim + ONE cut: S=8 with two-stage B staging (re-stage 64KB
// Blds once mid-kernel; barriers at pipeline-empty point). Halves acc_part
// round-trip (64->32MB). 512 blocks = exactly 2/CU @ 68KB LDS.

constexpr int N_ROWS = 8192;
constexpr int F_IN   = 128;
constexpr int F_OUT  = 64;
#define LRELU_A 0.2f
#define LOG2E   1.4426950408889634f

// workspace layout (bytes)
constexpr size_t OFF_WHT  = 0;                    // 1 MiB bf16 [f][row]
constexpr size_t OFF_SRC  = 1048576;              // 8192 f32 (x log2e)
constexpr size_t OFF_DST  = OFF_SRC + 32768;      // 8192 f32 (x log2e)
constexpr size_t OFF_LP   = OFF_DST + 32768;      // S*8192 f32
constexpr size_t OFF_ACC  = OFF_LP + 16 * 32768;  // up to 16 splits

typedef __attribute__((ext_vector_type(4))) float f32x4;
typedef __attribute__((ext_vector_type(4))) int   i32x4;
typedef __attribute__((ext_vector_type(8))) short s16x8;

static __device__ __forceinline__ short f2bf(float f) {
  unsigned u = __float_as_uint(f);
  u = (u + 0x7fffu + ((u >> 16) & 1u)) >> 16;  // RNE
  return (short)u;
}

// ---------------- Kernel 1: wh = x@w ; src/dst (x log2e) ; whT (bf16) -------
__global__ __launch_bounds__(256) void k1_proj(
    const float* __restrict__ x, const float* __restrict__ w,
    const float* __restrict__ a, short* __restrict__ whT,
    float* __restrict__ src, float* __restrict__ dst)
{
  const int lane = threadIdx.x & 63;   // = output feature f
  const int wid  = threadIdx.x >> 6;
  const int rowBase = blockIdx.x * 32 + wid * 8;   // 8 rows per wave

  float acc[8];
#pragma unroll
  for (int r = 0; r < 8; ++r) acc[r] = 0.0f;

#pragma unroll 1
  for (int kc = 0; kc < 4; ++kc) {     // K chunks of 32 — ONE wreg live
    float wreg[32];
#pragma unroll
    for (int kk = 0; kk < 32; ++kk)
      wreg[kk] = w[(kc * 32 + kk) * F_OUT + lane];   // coalesced
#pragma unroll
    for (int r = 0; r < 8; ++r) {
      const f32x4* xp = (const f32x4*)(x + (size_t)(rowBase + r) * F_IN + kc * 32);
#pragma unroll
      for (int q = 0; q < 8; ++q) {    // wave-uniform broadcast loads
        f32x4 xv = xp[q];
        acc[r] = fmaf(xv.x, wreg[4*q+0], acc[r]);
        acc[r] = fmaf(xv.y, wreg[4*q+1], acc[r]);
        acc[r] = fmaf(xv.z, wreg[4*q+2], acc[r]);
        acc[r] = fmaf(xv.w, wreg[4*q+3], acc[r]);
      }
    }
  }

  s16x8 hb;
#pragma unroll
  for (int r = 0; r < 8; ++r) hb[r] = f2bf(acc[r]);
  *(s16x8*)&whT[(size_t)lane * N_ROWS + rowBase] = hb;

  const float aS = a[lane];
  const float aD = a[F_OUT + lane];
#pragma unroll
  for (int r = 0; r < 8; ++r) {
    float ts = acc[r] * aS;
    float td = acc[r] * aD;
#pragma unroll
    for (int off = 32; off > 0; off >>= 1) {
      ts += __shfl_xor(ts, off, 64);
      td += __shfl_xor(td, off, 64);
    }
    if (lane == 0) {
      src[rowBase + r] = ts * LOG2E;   // log2-domain scores
      dst[rowBase + r] = td * LOG2E;
    }
  }
}

// ---------------- Kernel 2: depth-3 pipelined fused mask+exp+PV, 2-stage ----
// grid: (N/128, S) x 512 threads (8 waves x 16 rows). Loop vmem = adj only
// (plain cached), 3 register buffers, fully-unrolled inner NI=8 per stage.
// Two B-staging stages (SEG=512 cols each); accumulators carry across stages.
template<int S>
__global__ __launch_bounds__(512, 2) void k2_attn(
    const int* __restrict__ adj, const short* __restrict__ whT,
    const float* __restrict__ src, const float* __restrict__ dst,
    float* __restrict__ acc_part, float* __restrict__ l_part)
{
  constexpr int JLEN = N_ROWS / S;   // 1024 at S=8
  constexpr int SEG  = 512;          // columns per B-stage
  constexpr int NSTG = JLEN / SEG;   // 2
  constexpr int NI   = SEG / 64;     // 8
  __shared__ short Blds[64 * SEG];   // 64 KB, byte ^= (f&7)<<4 swizzle
  __shared__ float Dlds[JLEN];       // 4 KB

  const int tid  = threadIdx.x;
  const int lane = tid & 63;
  const int wid  = tid >> 6;
  const int s    = blockIdx.y;
  const int jbase = s * JLEN;
  const int rowg = blockIdx.x * 128 + wid * 16;
  const int r16  = lane & 15;
  const int kq   = lane >> 4;

  // dst slice for the whole block's j-range (staged once)
  for (int t4 = tid * 4; t4 < JLEN; t4 += 2048)
    *(f32x4*)&Dlds[t4] = *(const f32x4*)(dst + jbase + t4);

  const size_t arow = (size_t)(rowg + r16) * N_ROWS;
  const float sv = src[rowg + r16];               // already * log2e
  const int cswz = (r16 & 7) << 4;

  f32x4 acc0 = {0,0,0,0}, acc1 = {0,0,0,0}, acc2 = {0,0,0,0}, acc3 = {0,0,0,0};
  float lp = 0.0f;

  i32x4 A[3][4];                     // 3-deep adj pipeline (static after unroll)

#pragma unroll
  for (int st = 0; st < NSTG; ++st) {
    const int jb2 = jbase + st * SEG;
    if (st > 0) __syncthreads();     // all Blds ds_reads of prev stage done
    // ---- stage B segment (swizzled) ----
#pragma unroll
    for (int q = 0; q < 8; ++q) {        // 64 feats x 512 cols: 4096 x 16B
      const int m   = tid + q * 512;
      const int f   = m >> 6;
      const int c16 = m & 63;
      const s16x8 v = *(const s16x8*)(whT + (size_t)f * N_ROWS + jb2 + c16 * 8);
      *(s16x8*)((char*)Blds + f * (SEG * 2) + ((c16 * 16) ^ ((f & 7) << 4))) = v;
    }
    __syncthreads();                 // Blds (and Dlds on st=0) visible

    const int cb0 = jb2 + kq * 8;
    auto issueAdj = [&](int b, int i) {
      const int* p = adj + arow + cb0 + i * 64;    // plain cached loads
      A[b][0] = *(const i32x4*)(p);
      A[b][1] = *(const i32x4*)(p + 4);
      A[b][2] = *(const i32x4*)(p + 32);
      A[b][3] = *(const i32x4*)(p + 36);
    };

    issueAdj(0, 0); issueAdj(1, 1); issueAdj(2, 2);   // prologue: depth 3

#pragma unroll
    for (int i = 0; i < NI; ++i) {     // FULL unroll: A[i%3] indices static
#pragma unroll
      for (int h = 0; h < 2; ++h) {
        const int db = st * SEG + kq * 8 + i * 64 + h * 32;
        const f32x4 dA = *(const f32x4*)&Dlds[db];
        const f32x4 dB = *(const f32x4*)&Dlds[db + 4];
        const i32x4 aA = A[i % 3][2 * h];
        const i32x4 aB = A[i % 3][2 * h + 1];
        float p0, p1, p2, p3, p4, p5, p6, p7;
#define PE(pp, dd, aa) { float e = sv + (dd); e = fmaxf(e, LRELU_A * e); \
                         (pp) = ((aa) > 0) ? __builtin_amdgcn_exp2f(e) : 1.0f; }
        PE(p0, dA.x, aA.x) PE(p1, dA.y, aA.y) PE(p2, dA.z, aA.z) PE(p3, dA.w, aA.w)
        PE(p4, dB.x, aB.x) PE(p5, dB.y, aB.y) PE(p6, dB.z, aB.z) PE(p7, dB.w, aB.w)
#undef PE
        lp += ((p0 + p1) + (p2 + p3)) + ((p4 + p5) + (p6 + p7));
        union { s16x8 v; __hip_bfloat16 b[8]; } u;
        u.b[0] = __float2bfloat16(p0); u.b[1] = __float2bfloat16(p1);
        u.b[2] = __float2bfloat16(p2); u.b[3] = __float2bfloat16(p3);
        u.b[4] = __float2bfloat16(p4); u.b[5] = __float2bfloat16(p5);
        u.b[6] = __float2bfloat16(p6); u.b[7] = __float2bfloat16(p7);
        const char* bb = (const char*)Blds;
        const int colb = (i * 64 + h * 32 + kq * 8) * 2;
        const s16x8 b0 = *(const s16x8*)(bb + (0 * 16 + r16) * (SEG * 2) + (colb ^ cswz));
        const s16x8 b1 = *(const s16x8*)(bb + (1 * 16 + r16) * (SEG * 2) + (colb ^ cswz));
        const s16x8 b2 = *(const s16x8*)(bb + (2 * 16 + r16) * (SEG * 2) + (colb ^ cswz));
        const s16x8 b3 = *(const s16x8*)(bb + (3 * 16 + r16) * (SEG * 2) + (colb ^ cswz));
        acc0 = __builtin_amdgcn_mfma_f32_16x16x32_bf16(u.v, b0, acc0, 0, 0, 0);
        acc1 = __builtin_amdgcn_mfma_f32_16x16x32_bf16(u.v, b1, acc1, 0, 0, 0);
        acc2 = __builtin_amdgcn_mfma_f32_16x16x32_bf16(u.v, b2, acc2, 0, 0, 0);
        acc3 = __builtin_amdgcn_mfma_f32_16x16x32_bf16(u.v, b3, acc3, 0, 0, 0);
      }
      if (i + 3 < NI) issueAdj(i % 3, i + 3);   // refill just-freed buffer
    }
  }

  // ---- epilogue ----
  lp += __shfl_xor(lp, 16, 64);       // lanes {l, l^16, l^32, l^48}: same row
  lp += __shfl_xor(lp, 32, 64);
  if (lane < 16) l_part[(size_t)s * N_ROWS + rowg + lane] = lp;

  // C/D layout: col(feat) = lane&15, row = (lane>>4)*4 + reg
#define STORE_ACC(av, nt) _Pragma("unroll") \
  for (int rg = 0; rg < 4; ++rg) { \
    const int row = rowg + kq * 4 + rg; \
    acc_part[((size_t)s * N_ROWS + row) * F_OUT + (nt) * 16 + r16] = (av)[rg]; \
  }
  STORE_ACC(acc0, 0) STORE_ACC(acc1, 1) STORE_ACC(acc2, 2) STORE_ACC(acc3, 3)
#undef STORE_ACC
}

// ---------------- Kernel 3: combine partials, normalize, ELU ----------------
template<int S>
__global__ __launch_bounds__(256) void k3_combine(
    const float* __restrict__ acc_part, const float* __restrict__ l_part,
    float* __restrict__ out)
{
  const int idx = blockIdx.x * 256 + threadIdx.x;  // over N*F/4
  const int row = idx >> 4;          // F_OUT/4 = 16
  const int f4  = idx & 15;
  f32x4 h = {0.f, 0.f, 0.f, 0.f};
  float l = 0.f;
#pragma unroll
  for (int s = 0; s < S; ++s) {
    h += *(const f32x4*)(acc_part + ((size_t)s * N_ROWS + row) * F_OUT + 4 * f4);
    l += l_part[(size_t)s * N_ROWS + row];
  }
  const float inv = 1.0f / l;
  f32x4 o;
  {
    float v0 = h.x * inv; o.x = v0 > 0.f ? v0 : (__expf(v0) - 1.0f);
    float v1 = h.y * inv; o.y = v1 > 0.f ? v1 : (__expf(v1) - 1.0f);
    float v2 = h.z * inv; o.z = v2 > 0.f ? v2 : (__expf(v2) - 1.0f);
    float v3 = h.w * inv; o.w = v3 > 0.f ? v3 : (__expf(v3) - 1.0f);
  }
  *(f32x4*)(out + (size_t)row * F_OUT + 4 * f4) = o;
}

// ---------------- launch ----------------
extern "C" void kernel_launch(void* const* d_in, const int* in_sizes, int n_in,
                              void* d_out, int out_size, void* d_ws, size_t ws_size,
                              hipStream_t stream) {
  const float* x   = (const float*)d_in[0];
  const int*   adj = (const int*)d_in[1];
  const float* w   = (const float*)d_in[2];
  const float* a   = (const float*)d_in[3];
  float* out = (float*)d_out;
  char* ws = (char*)d_ws;

  short* whT      = (short*)(ws + OFF_WHT);
  float* src      = (float*)(ws + OFF_SRC);
  float* dst      = (float*)(ws + OFF_DST);
  float* l_part   = (float*)(ws + OFF_LP);
  float* acc_part = (float*)(ws + OFF_ACC);

  k1_proj<<<N_ROWS / 32, 256, 0, stream>>>(x, w, a, whT, src, dst);
  k2_attn<8><<<dim3(N_ROWS / 128, 8), 512, 0, stream>>>(adj, whT, src, dst,
                                                        acc_part, l_part);
  k3_combine<8><<<(N_ROWS * F_OUT / 4) / 256, 256, 0, stream>>>(acc_part, l_part, out);
}